// Round 4
// baseline (288.373 us; speedup 1.0000x reference)
//
#include <hip/hip_runtime.h>
#include <stdint.h>
#include <stddef.h>

#define B_  16
#define U_  512
#define LX_ 1024
#define LY_ 1024
#define H_  8
#define D_  64

typedef unsigned short ushort_t;
typedef unsigned int   uint_t;
typedef __bf16 v8bf  __attribute__((ext_vector_type(8)));
typedef float  v16f  __attribute__((ext_vector_type(16)));

__device__ __forceinline__ ushort_t bf16u(float f) {
    uint_t u = __float_as_uint(f);
    uint_t r = (u + 0x7FFFu + ((u >> 16) & 1u)) >> 16;
    return (ushort_t)r;
}
__device__ __forceinline__ float bfu2f(ushort_t u) {
    return __uint_as_float(((uint_t)u) << 16);
}
// async global->LDS, 16B/lane. LDS dest is wave-uniform base + lane*16, so
// swizzling must be applied to the GLOBAL source chunk, not the LDS address.
__device__ __forceinline__ void gload16(const void* g, void* l) {
    auto gp = (const __attribute__((address_space(1))) uint32_t*)(uintptr_t)g;
    auto lp = (__attribute__((address_space(3))) uint32_t*)(uintptr_t)l;
    __builtin_amdgcn_global_load_lds(gp, lp, 16, 0, 0);
}

// ---------------------------------------------------------------------------
// Fused prep: one dispatch, blockIdx-partitioned.
//   [0,    4096): castT  -- x,y [b][u][l] f32 -> [b][l][u] bf16 (64x64 tiles)
//   [4096, 8192): nelmask -- mask -> ballot bits + n_el (self-detecting width)
//   [8192, 8960): castw  -- wq/wk/wo f32 -> bf16
// ---------------------------------------------------------------------------
__global__ __launch_bounds__(256) void prep_kernel(const float* __restrict__ X,
                                                   const float* __restrict__ Y,
                                                   const void* __restrict__ mask,
                                                   const float* __restrict__ wq,
                                                   const float* __restrict__ wk,
                                                   const float* __restrict__ wo,
                                                   ushort_t* __restrict__ XT,
                                                   ushort_t* __restrict__ YT,
                                                   ushort_t* __restrict__ wqb,
                                                   ushort_t* __restrict__ wkb,
                                                   ushort_t* __restrict__ wob,
                                                   float* __restrict__ nel,
                                                   uint_t* __restrict__ mb) {
    __shared__ ushort_t T[64][72];
    __shared__ int s;
    const int tid = threadIdx.x;
    const int bid = blockIdx.x;

    if (bid < 4096) {
        // ---- castT ----
        const int l0 = (bid & 15) * 64;
        const int u0 = ((bid >> 4) & 7) * 64;
        const int z  = bid >> 7;            // 0..31
        const int b  = z & 15;
        const int sel = z >> 4;
        const float* S = sel ? Y : X;
        ushort_t*  Dst = sel ? YT : XT;
        #pragma unroll
        for (int e = 0; e < 4; ++e) {
            int ci = e * 256 + tid;          // 0..1023 float4s
            int r = ci >> 4, c4 = (ci & 15) * 4;
            float4 v = *(const float4*)&S[((size_t)(b * U_ + u0 + r) << 10) + l0 + c4];
            T[r][c4 + 0] = bf16u(v.x); T[r][c4 + 1] = bf16u(v.y);
            T[r][c4 + 2] = bf16u(v.z); T[r][c4 + 3] = bf16u(v.w);
        }
        __syncthreads();
        #pragma unroll
        for (int e = 0; e < 2; ++e) {
            int ci = e * 256 + tid;          // 0..511 chunks of 8
            int lr = ci >> 3, cc = ci & 7;
            ushort_t tmp[8];
            #pragma unroll
            for (int j = 0; j < 8; ++j) tmp[j] = T[cc * 8 + j][lr];
            *(uint4*)&Dst[((size_t)((b << 10) + l0 + lr)) * U_ + u0 + cc * 8] = *(uint4*)tmp;
        }
    } else if (bid < 8192) {
        // ---- nelmask with per-block width detect (first 4KB, L2-hot) ----
        const uint_t* mw = (const uint_t*)mask;
        if (tid == 0) s = 0;
        __syncthreads();
        int c = 0;
        for (int i = tid; i < 1024; i += 256) c += (mw[i] <= 1u) ? 1 : 0;
        atomicAdd(&s, c);
        __syncthreads();
        const int isInt = (s >= 1000) ? 1 : 0;

        int row  = (bid - 4096) * 4 + (tid >> 6);   // b*1024 + x
        int lane = tid & 63;
        const uint8_t* m8  = (const uint8_t*)mask + (size_t)row * LY_;
        const int*     m32 = (const int*)mask + (size_t)row * LY_;
        int cnt = 0;
        for (int yg = 0; yg < LY_ / 64; ++yg) {
            int yy = yg * 64 + lane;
            bool p = isInt ? (m32[yy] != 0) : (m8[yy] != 0);
            unsigned long long bal = __ballot(p);
            if (lane == 0) {
                mb[(size_t)row * 32 + yg * 2]     = (uint_t)bal;
                mb[(size_t)row * 32 + yg * 2 + 1] = (uint_t)(bal >> 32);
                cnt += __popcll(bal);
            }
        }
        if (lane == 0) nel[row] = (float)(cnt > 0 ? cnt : 1);
    } else {
        // ---- castw ----
        int cb = bid - 8192;                // 0..767
        int selw = cb >> 8;
        const float* sw = selw == 0 ? wq : (selw == 1 ? wk : wo);
        ushort_t*    dw = selw == 0 ? wqb : (selw == 1 ? wkb : wob);
        int i = ((cb & 255) * 256 + tid) * 4;
        float4 v = *(const float4*)&sw[i];
        ushort4 p;
        p.x = bf16u(v.x); p.y = bf16u(v.y); p.z = bf16u(v.z); p.w = bf16u(v.w);
        *(ushort4*)&dw[i] = p;
    }
}

// ---------------------------------------------------------------------------
// Merged Q/K GEMM, one full-device dispatch (1024 blocks).
//   id < 512 : QT[b][x][u]  = xT[b] (M=1024) x wq (N=512)
//   id >= 512: Ka[b][u][y]  = wk (M=512) x yT[b] (N=1024)
//              + dual-write Kb[b][h][y][d] (transpose) -> kills ktranspose.
// Kb scatter stores (2B, stride 128B per lane) land in a 16KB L2-resident
// region per block; L2 write-combining absorbs them.
// ---------------------------------------------------------------------------
__global__ __launch_bounds__(256) void gemm_qk(const ushort_t* __restrict__ xT,
                                               const ushort_t* __restrict__ wqb,
                                               const ushort_t* __restrict__ wkb,
                                               const ushort_t* __restrict__ yT,
                                               ushort_t* __restrict__ QT,
                                               ushort_t* __restrict__ Ka,
                                               ushort_t* __restrict__ Kb) {
    __shared__ __align__(16) ushort_t As[128 * 64];
    __shared__ __align__(16) ushort_t Bs[128 * 64];
    const int tid = threadIdx.x;
    const int id  = blockIdx.x;
    const int isK = id >> 9;
    const int lid = id & 511;
    const int b   = lid >> 5;
    int m0, n0, ldOut;
    const ushort_t *Ab, *Bb;
    ushort_t* Ob;
    if (!isK) {
        n0 = (lid & 3) * 128; m0 = ((lid >> 2) & 7) * 128;
        Ab = xT + (size_t)b * (LX_ * U_); Bb = wqb;
        Ob = QT + (size_t)b * (LX_ * U_); ldOut = U_;
    } else {
        n0 = (lid & 7) * 128; m0 = ((lid >> 3) & 3) * 128;
        Ab = wkb; Bb = yT + (size_t)b * (LY_ * U_);
        Ob = Ka + (size_t)b * (U_ * LY_); ldOut = LY_;
    }

    const int w = tid >> 6, lane = tid & 63, lo = lane & 31, hi = lane >> 5;
    const int wm = (w >> 1) * 64, wn = (w & 1) * 64;

    v16f acc00, acc01, acc10, acc11;
    #pragma unroll
    for (int i = 0; i < 16; ++i) { acc00[i] = 0.f; acc01[i] = 0.f; acc10[i] = 0.f; acc11[i] = 0.f; }

    for (int kk = 0; kk < 8; ++kk) {
        const int k0 = kk * 64;
        #pragma unroll
        for (int e = 0; e < 4; ++e) {
            int ci = e * 256 + tid;          // 0..1023 16B chunks
            int r = ci >> 3, c = ci & 7;
            int g = (c ^ (r & 7)) << 3;      // swizzle on SOURCE chunk
            gload16(&Ab[(size_t)(m0 + r) * U_ + k0 + g], &As[ci * 8]);
            gload16(&Bb[(size_t)(n0 + r) * U_ + k0 + g], &Bs[ci * 8]);
        }
        __syncthreads();
        #pragma unroll
        for (int ks = 0; ks < 4; ++ks) {
            int ch = ks * 2 + hi;
            int rA0 = wm + lo, rA1 = wm + 32 + lo;
            int rB0 = wn + lo, rB1 = wn + 32 + lo;
            v8bf a0 = *(v8bf*)&As[rA0 * 64 + ((ch ^ (rA0 & 7)) << 3)];
            v8bf a1 = *(v8bf*)&As[rA1 * 64 + ((ch ^ (rA1 & 7)) << 3)];
            v8bf b0 = *(v8bf*)&Bs[rB0 * 64 + ((ch ^ (rB0 & 7)) << 3)];
            v8bf b1 = *(v8bf*)&Bs[rB1 * 64 + ((ch ^ (rB1 & 7)) << 3)];
            acc00 = __builtin_amdgcn_mfma_f32_32x32x16_bf16(a0, b0, acc00, 0, 0, 0);
            acc01 = __builtin_amdgcn_mfma_f32_32x32x16_bf16(a0, b1, acc01, 0, 0, 0);
            acc10 = __builtin_amdgcn_mfma_f32_32x32x16_bf16(a1, b0, acc10, 0, 0, 0);
            acc11 = __builtin_amdgcn_mfma_f32_32x32x16_bf16(a1, b1, acc11, 0, 0, 0);
        }
        __syncthreads();
    }

    #pragma unroll
    for (int mi = 0; mi < 2; ++mi) {
        #pragma unroll
        for (int nj = 0; nj < 2; ++nj) {
            v16f c = mi ? (nj ? acc11 : acc10) : (nj ? acc01 : acc00);
            int n = n0 + wn + nj * 32 + lo;
            #pragma unroll
            for (int r = 0; r < 16; ++r) {
                int m = m0 + wm + mi * 32 + (r & 3) + 8 * (r >> 2) + 4 * hi;
                ushort_t v = bf16u(c[r]);
                Ob[(size_t)m * ldOut + n] = v;
                if (isK)
                    Kb[(((size_t)(b * H_ + (m >> 6)) << 10) + n) * D_ + (m & 63)] = v;
            }
        }
    }
}

// ---------------------------------------------------------------------------
// O-GEMM: Out[b][m][n] = sum_k A[m][k] * B_b[n][k], fp32 out.
// ---------------------------------------------------------------------------
template <int OUTF32>
__global__ __launch_bounds__(256) void gemm_mfma(const ushort_t* __restrict__ A, size_t aStr,
                                                 const ushort_t* __restrict__ Bm, size_t bStr,
                                                 void* __restrict__ Out, size_t oStr, int ldOut) {
    const int n0 = blockIdx.x * 128;
    const int m0 = blockIdx.y * 128;
    const int b  = blockIdx.z;
    __shared__ __align__(16) ushort_t As[128 * 64];
    __shared__ __align__(16) ushort_t Bs[128 * 64];
    const int tid = threadIdx.x;
    const ushort_t* Ab = A + aStr * b;
    const ushort_t* Bb = Bm + bStr * b;

    const int w = tid >> 6, lane = tid & 63, lo = lane & 31, hi = lane >> 5;
    const int wm = (w >> 1) * 64, wn = (w & 1) * 64;

    v16f acc00, acc01, acc10, acc11;
    #pragma unroll
    for (int i = 0; i < 16; ++i) { acc00[i] = 0.f; acc01[i] = 0.f; acc10[i] = 0.f; acc11[i] = 0.f; }

    for (int kk = 0; kk < 8; ++kk) {
        const int k0 = kk * 64;
        #pragma unroll
        for (int e = 0; e < 4; ++e) {
            int ci = e * 256 + tid;          // 0..1023 16B chunks
            int r = ci >> 3, c = ci & 7;
            int g = (c ^ (r & 7)) << 3;      // swizzle on SOURCE chunk
            gload16(&Ab[(size_t)(m0 + r) * U_ + k0 + g], &As[ci * 8]);
            gload16(&Bb[(size_t)(n0 + r) * U_ + k0 + g], &Bs[ci * 8]);
        }
        __syncthreads();
        #pragma unroll
        for (int ks = 0; ks < 4; ++ks) {
            int ch = ks * 2 + hi;
            int rA0 = wm + lo, rA1 = wm + 32 + lo;
            int rB0 = wn + lo, rB1 = wn + 32 + lo;
            v8bf a0 = *(v8bf*)&As[rA0 * 64 + ((ch ^ (rA0 & 7)) << 3)];
            v8bf a1 = *(v8bf*)&As[rA1 * 64 + ((ch ^ (rA1 & 7)) << 3)];
            v8bf b0 = *(v8bf*)&Bs[rB0 * 64 + ((ch ^ (rB0 & 7)) << 3)];
            v8bf b1 = *(v8bf*)&Bs[rB1 * 64 + ((ch ^ (rB1 & 7)) << 3)];
            acc00 = __builtin_amdgcn_mfma_f32_32x32x16_bf16(a0, b0, acc00, 0, 0, 0);
            acc01 = __builtin_amdgcn_mfma_f32_32x32x16_bf16(a0, b1, acc01, 0, 0, 0);
            acc10 = __builtin_amdgcn_mfma_f32_32x32x16_bf16(a1, b0, acc10, 0, 0, 0);
            acc11 = __builtin_amdgcn_mfma_f32_32x32x16_bf16(a1, b1, acc11, 0, 0, 0);
        }
        __syncthreads();
    }

    #pragma unroll
    for (int mi = 0; mi < 2; ++mi) {
        #pragma unroll
        for (int nj = 0; nj < 2; ++nj) {
            v16f c = mi ? (nj ? acc11 : acc10) : (nj ? acc01 : acc00);
            int n = n0 + wn + nj * 32 + lo;
            #pragma unroll
            for (int r = 0; r < 16; ++r) {
                int m = m0 + wm + mi * 32 + (r & 3) + 8 * (r >> 2) + 4 * hi;
                size_t addr = oStr * b + (size_t)m * ldOut + n;
                if (OUTF32) ((float*)Out)[addr] = c[r];
                else        ((ushort_t*)Out)[addr] = bf16u(c[r]);
            }
        }
    }
}

// ---------------------------------------------------------------------------
// Fused bf16-MFMA attention, 4-way x-split, in-register S->C handoff, 32 KB.
// (unchanged from R3: VGPR=60, no spill, 4 blocks/CU co-resident)
// ---------------------------------------------------------------------------
typedef uint_t v2u __attribute__((ext_vector_type(2)));

// s: 16 f32 of one 32x32 S^T block (D-layout, cols = this lane's x). wbh:
// mask word for the block's 32 y's >> (hi*8).  fr[t]: B-operand fragment for
// k-step t (t=0: y_off 0..15, t=1: 16..31 relative to the block).
__device__ __forceinline__ void conv_sblock(const v16f& s, uint_t wbh, v8bf* fr) {
    uint_t pk[8];
    #pragma unroll
    for (int i = 0; i < 8; ++i) {
        float f0 = fmaxf(s[2 * i + 0], 0.f);
        float f1 = fmaxf(s[2 * i + 1], 0.f);
        uint_t r;
        asm("v_cvt_pk_bf16_f32 %0, %1, %2" : "=v"(r) : "v"(f0), "v"(f1));
        pk[i] = r;
    }
    #pragma unroll
    for (int t = 0; t < 2; ++t) {
        // swap(A,B): A'[32+i]=B[i], B'[i]=A[32+i]
        auto ra = __builtin_amdgcn_permlane32_swap(pk[4 * t + 0], pk[4 * t + 2], false, false);
        auto rb = __builtin_amdgcn_permlane32_swap(pk[4 * t + 1], pk[4 * t + 3], false, false);
        uint_t w0 = ra[0];   // j={0,1}:  y_off = t*16 + hi*8 + {0,1}
        uint_t w1 = rb[0];   // j={2,3}
        uint_t w2 = ra[1];   // j={4,5}
        uint_t w3 = rb[1];   // j={6,7}
        uint_t u0 = wbh >> (t * 16 + 0);
        uint_t u1 = wbh >> (t * 16 + 2);
        uint_t u2 = wbh >> (t * 16 + 4);
        uint_t u3 = wbh >> (t * 16 + 6);
        w0 &= ((u0 & 1u) * 0xFFFFu) | ((u0 & 2u) * 0x7FFF8000u);
        w1 &= ((u1 & 1u) * 0xFFFFu) | ((u1 & 2u) * 0x7FFF8000u);
        w2 &= ((u2 & 1u) * 0xFFFFu) | ((u2 & 2u) * 0x7FFF8000u);
        w3 &= ((u3 & 1u) * 0xFFFFu) | ((u3 & 2u) * 0x7FFF8000u);
        union { uint_t u[4]; v8bf b; } cv;
        cv.u[0] = w0; cv.u[1] = w1; cv.u[2] = w2; cv.u[3] = w3;
        fr[t] = cv.b;
    }
}

__global__ __launch_bounds__(256, 4) void attn_mfma(const ushort_t* __restrict__ QTg,
                                                    const ushort_t* __restrict__ Ka_g,
                                                    const ushort_t* __restrict__ Kb_g,
                                                    const uint_t* __restrict__ mbits,
                                                    const float* __restrict__ nel,
                                                    ushort_t* __restrict__ ETg) {
    const int tid = threadIdx.x;
    const int id  = blockIdx.x;
    const int bh  = id & 127;          // same-bh blocks -> same XCD (id%8 heuristic)
    const int x0g = (id >> 7) * 128;
    const int b = bh >> 3, h = bh & 7;

    // 32 KB: KB dbuf [0,16KB) | KA dbuf [16KB,32KB).  Reused post-loop as Et.
    __shared__ __align__(16) ushort_t SM[4 * 4096];

    const int w    = tid >> 6;         // x-quarter index 0..3
    const int lane = tid & 63;
    const int lo   = lane & 31;
    const int hi   = lane >> 5;
    const int xq   = w * 32;           // x-quarter base within the 128-x tile

    const ushort_t* KaBase = Ka_g + ((size_t)(b * U_ + h * D_)) * LY_;
    const ushort_t* KbBase = Kb_g + ((size_t)(b * H_ + h)) * LY_ * D_;
    const int bx = b * LX_ + x0g;
    const int xg = bx + xq + lo;       // this lane's global x row

    // ---- stage first K tile into buffer 0 ----
    #pragma unroll
    for (int e = 0; e < 2; ++e) {
        int ci = e * 256 + tid;
        int r = ci >> 3, c = ci & 7;
        int g8 = (c ^ (r & 7)) << 3;
        gload16(&KbBase[(size_t)r * D_ + g8], &SM[ci * 8]);
        gload16(&KaBase[(size_t)r * LY_ + g8], &SM[8192 + ci * 8]);
    }

    // ---- Q B-fragments straight from global (loop-invariant, 16 VGPR) ----
    v8bf qf[4];
    {
        const ushort_t* q0 = QTg + (size_t)xg * U_ + h * D_;
        #pragma unroll
        for (int kt = 0; kt < 4; ++kt) qf[kt] = *(const v8bf*)&q0[(kt * 2 + hi) * 8];
    }

    // full-C accumulators for this x-quarter: acc0 = d 0..31, acc1 = d 32..63
    v16f acc0, acc1;
    #pragma unroll
    for (int i = 0; i < 16; ++i) { acc0[i] = 0.f; acc1[i] = 0.f; }

    __syncthreads();   // first tile staged (drains gload_lds)

    for (int tt = 0; tt < 16; ++tt) {
        ushort_t* KBc = SM + (tt & 1) * 4096;
        ushort_t* KAc = SM + 8192 + (tt & 1) * 4096;

        // prefetch next tile into other buffer; drained by end-of-tile barrier
        if (tt < 15) {
            ushort_t* KBn = SM + ((tt + 1) & 1) * 4096;
            ushort_t* KAn = SM + 8192 + ((tt + 1) & 1) * 4096;
            const int yn = tt * 64 + 64;
            #pragma unroll
            for (int e = 0; e < 2; ++e) {
                int ci = e * 256 + tid;
                int r = ci >> 3, c = ci & 7;
                int g8 = (c ^ (r & 7)) << 3;
                gload16(&KbBase[(size_t)(yn + r) * D_ + g8], &KBn[ci * 8]);
                gload16(&KaBase[(size_t)r * LY_ + yn + g8], &KAn[ci * 8]);
            }
        }
        // both 32-y mask words for this lane's x row, one 8B load
        v2u wb = *(const v2u*)&mbits[(size_t)xg * 32 + tt * 2];

        // ---- S-phase, y-block 0 (y0..y0+31): S^T = Kb * Q^T ----
        v8bf fr0[2], fr1[2];
        {
            v16f s;
            #pragma unroll
            for (int i = 0; i < 16; ++i) s[i] = 0.f;
            #pragma unroll
            for (int kt = 0; kt < 4; ++kt) {
                int ch = kt * 2 + hi;
                v8bf a = *(v8bf*)&KBc[lo * 64 + ((ch ^ (lo & 7)) << 3)];
                s = __builtin_amdgcn_mfma_f32_32x32x16_bf16(a, qf[kt], s, 0, 0, 0);
            }
            conv_sblock(s, wb[0] >> (hi * 8), fr0);
        }
        // ---- S-phase, y-block 1 (y0+32..y0+63) ----
        {
            v16f s;
            #pragma unroll
            for (int i = 0; i < 16; ++i) s[i] = 0.f;
            #pragma unroll
            for (int kt = 0; kt < 4; ++kt) {
                int ch = kt * 2 + hi;
                v8bf a = *(v8bf*)&KBc[(32 + lo) * 64 + ((ch ^ ((32 + lo) & 7)) << 3)];
                s = __builtin_amdgcn_mfma_f32_32x32x16_bf16(a, qf[kt], s, 0, 0, 0);
            }
            conv_sblock(s, wb[1] >> (hi * 8), fr1);
        }

        // ---- C-phase: C[d][x-quarter] += Ka * S over all 64 y ----
        #pragma unroll
        for (int kt = 0; kt < 4; ++kt) {
            int ch = kt * 2 + hi;
            v8bf frk = (kt < 2) ? fr0[kt] : fr1[kt - 2];
            v8bf a0 = *(v8bf*)&KAc[lo * 64 + ((ch ^ (lo & 7)) << 3)];
            v8bf a1 = *(v8bf*)&KAc[(32 + lo) * 64 + ((ch ^ ((32 + lo) & 7)) << 3)];
            acc0 = __builtin_amdgcn_mfma_f32_32x32x16_bf16(a0, frk, acc0, 0, 0, 0);
            acc1 = __builtin_amdgcn_mfma_f32_32x32x16_bf16(a1, frk, acc1, 0, 0, 0);
        }
        __syncthreads();   // drains prefetch vmcnt + protects buffer swap
    }

    // ---- epilogue: E = 0.5*Q + C*(0.0625/nel) -> Et (dead K region) ----
    // Wave owns full C for its x-quarter; no cross-wave reduction needed.
    {
        ushort_t* Et = SM;
        const int xl = xq + lo;
        float invn = 0.0625f / nel[xg];
        const ushort_t* qg = QTg + (size_t)xg * U_ + h * D_ + 4 * hi;
        #pragma unroll
        for (int half = 0; half < 2; ++half) {
            const v16f& c = half ? acc1 : acc0;
            #pragma unroll
            for (int q = 0; q < 4; ++q) {
                int d0 = half * 32 + q * 8 + 4 * hi;               // d0&7 == 4*hi
                ushort_t q4[4];
                *(uint2*)q4 = *(const uint2*)&qg[half * 32 + q * 8];
                ushort_t e4[4];
                e4[0] = bf16u(0.5f * bfu2f(q4[0]) + c[q * 4 + 0] * invn);
                e4[1] = bf16u(0.5f * bfu2f(q4[1]) + c[q * 4 + 1] * invn);
                e4[2] = bf16u(0.5f * bfu2f(q4[2]) + c[q * 4 + 2] * invn);
                e4[3] = bf16u(0.5f * bfu2f(q4[3]) + c[q * 4 + 3] * invn);
                int base = xl * 64 + ((((d0 >> 3) ^ (xl & 7)) << 3) | (4 * hi));
                *(uint2*)&Et[base] = *(uint2*)e4;
            }
        }
    }
    __syncthreads();
    // ---- write ET[b][x][h*64+d] coalesced (un-swizzle on read) ----
    #pragma unroll
    for (int e = 0; e < 4; ++e) {
        int idx = e * 256 + tid;
        int row = idx >> 3, cc = idx & 7;
        uint4 v = *(const uint4*)&SM[row * 64 + ((cc ^ (row & 7)) << 3)];
        *(uint4*)&ETg[((size_t)(bx + row)) * U_ + h * D_ + cc * 8] = v;
    }
}

// ---------------------------------------------------------------------------
extern "C" void kernel_launch(void* const* d_in, const int* in_sizes, int n_in,
                              void* d_out, int out_size, void* d_ws, size_t ws_size,
                              hipStream_t stream) {
    const float* x    = (const float*)d_in[0];
    const float* y    = (const float*)d_in[1];
    const void*  mask = d_in[2];
    const float* wq   = (const float*)d_in[3];
    const float* wk   = (const float*)d_in[4];
    const float* wo   = (const float*)d_in[5];

    // ws layout (bytes):
    //   [0,        16777216)  xT bf16   -> later ET bf16
    //   [16777216, 33554432)  yT bf16
    //   [33554432, 50331648)  Ka bf16
    //   [50331648, 50855936)  wq bf16
    //   [50855936, 51380224)  wk bf16
    //   [51380224, 51904512)  wo bf16
    //   [51904512, 54001664)  maskBits u32
    //   [54001664, 54067200)  nel f32
    // d_out (33.5 MB fp32) moonlights as: QT bf16 [0,16MB) | Kb bf16 [16MB,32MB)
    // until the O-GEMM overwrites it.
    char* wsb = (char*)d_ws;
    ushort_t* xT    = (ushort_t*)(wsb);
    ushort_t* yT    = (ushort_t*)(wsb + 16777216);
    ushort_t* Ka    = (ushort_t*)(wsb + 33554432);
    ushort_t* wqb   = (ushort_t*)(wsb + 50331648);
    ushort_t* wkb   = (ushort_t*)(wsb + 50855936);
    ushort_t* wob   = (ushort_t*)(wsb + 51380224);
    uint_t*   mbits = (uint_t*)(wsb + 51904512);
    float*    nel   = (float*)(wsb + 54001664);
    ushort_t* ET    = xT;                 // alias: xT dead after Q-GEMM
    ushort_t* QT    = (ushort_t*)d_out;                         // [0, 16MB)
    ushort_t* Kb    = (ushort_t*)d_out + (size_t)B_ * LX_ * U_; // [16MB, 32MB)

    prep_kernel<<<8960, 256, 0, stream>>>(x, y, mask, wq, wk, wo,
                                          xT, yT, wqb, wkb, wob, nel, mbits);
    gemm_qk<<<1024, 256, 0, stream>>>(xT, wqb, wkb, yT, QT, Ka, Kb);
    attn_mfma<<<1024, 256, 0, stream>>>(QT, Ka, Kb, mbits, nel, ET);
    // out[b][u][x] fp32 = wo (M=512) x ET[b] (N=1024)
    gemm_mfma<1><<<dim3(8, 4, B_), 256, 0, stream>>>(
        wob, 0, ET, (size_t)LX_ * U_, d_out, (size_t)U_ * LX_, LX_);
}

// Round 5
// 279.254 us; speedup vs baseline: 1.0327x; 1.0327x over previous
//
#include <hip/hip_runtime.h>
#include <stdint.h>
#include <stddef.h>

#define B_  16
#define U_  512
#define LX_ 1024
#define LY_ 1024
#define H_  8
#define D_  64

typedef unsigned short ushort_t;
typedef unsigned int   uint_t;
typedef __bf16 v8bf  __attribute__((ext_vector_type(8)));
typedef float  v16f  __attribute__((ext_vector_type(16)));

__device__ __forceinline__ ushort_t bf16u(float f) {
    uint_t u = __float_as_uint(f);
    uint_t r = (u + 0x7FFFu + ((u >> 16) & 1u)) >> 16;
    return (ushort_t)r;
}
__device__ __forceinline__ float bfu2f(ushort_t u) {
    return __uint_as_float(((uint_t)u) << 16);
}
// RNE-pack two fp32 -> packed bf16x2 (low=f0) using v_perm_b32.
__device__ __forceinline__ uint_t pkbf16(float f0, float f1) {
    uint_t u0 = __float_as_uint(f0), u1 = __float_as_uint(f1);
    u0 = u0 + 0x7FFFu + ((u0 >> 16) & 1u);
    u1 = u1 + 0x7FFFu + ((u1 >> 16) & 1u);
    return __builtin_amdgcn_perm(u1, u0, 0x07060302u);
}
// async global->LDS, 16B/lane. LDS dest is wave-uniform base + lane*16, so
// swizzling must be applied to the GLOBAL source chunk, not the LDS address.
__device__ __forceinline__ void gload16(const void* g, void* l) {
    auto gp = (const __attribute__((address_space(1))) uint32_t*)(uintptr_t)g;
    auto lp = (__attribute__((address_space(3))) uint32_t*)(uintptr_t)l;
    __builtin_amdgcn_global_load_lds(gp, lp, 16, 0, 0);
}

// ---------------------------------------------------------------------------
// Fused prep: one dispatch, blockIdx-partitioned.
//   [0,    4096): castT  -- x,y [b][u][l] f32 -> [b][l][u] bf16 (64x64 tiles)
//                 v2: bf16x2-packed b32 LDS transpose (pad-33) + v_perm
//   [4096, 8192): nelmask -- mask -> ballot bits + n_el (wave-local detect)
//   [8192, 8960): castw  -- wq/wk/wo f32 -> bf16
// ---------------------------------------------------------------------------
__global__ __launch_bounds__(256) void prep_kernel(const float* __restrict__ X,
                                                   const float* __restrict__ Y,
                                                   const void* __restrict__ mask,
                                                   const float* __restrict__ wq,
                                                   const float* __restrict__ wk,
                                                   const float* __restrict__ wo,
                                                   ushort_t* __restrict__ XT,
                                                   ushort_t* __restrict__ YT,
                                                   ushort_t* __restrict__ wqb,
                                                   ushort_t* __restrict__ wkb,
                                                   ushort_t* __restrict__ wob,
                                                   float* __restrict__ nel,
                                                   uint_t* __restrict__ mb) {
    __shared__ uint_t Tp[64 * 33];      // [u][l/2] bf16x2, pad 1 dword/row
    const int tid = threadIdx.x;
    const int bid = blockIdx.x;

    if (bid < 4096) {
        // ---- castT v2 ----
        const int l0 = (bid & 15) * 64;
        const int u0 = ((bid >> 4) & 7) * 64;
        const int z  = bid >> 7;            // 0..31
        const int b  = z & 15;
        const int sel = z >> 4;
        const float* S = sel ? Y : X;
        ushort_t*  Dst = sel ? YT : XT;
        #pragma unroll
        for (int e = 0; e < 4; ++e) {
            int ci = e * 256 + tid;          // 0..1023 float4s
            int r = ci >> 4, c4 = (ci & 15) * 4;
            float4 v = *(const float4*)&S[((size_t)(b * U_ + u0 + r) << 10) + l0 + c4];
            Tp[r * 33 + (c4 >> 1)]     = pkbf16(v.x, v.y);
            Tp[r * 33 + (c4 >> 1) + 1] = pkbf16(v.z, v.w);
        }
        __syncthreads();
        #pragma unroll
        for (int e = 0; e < 2; ++e) {
            int ci = e * 256 + tid;          // 0..511 chunks of 8 u
            int lr = ci >> 3, cc = ci & 7;
            int l2 = lr >> 1;
            // even l: take lo16 halves; odd l: hi16 halves
            uint_t sel8 = (lr & 1) ? 0x07060302u : 0x05040100u;
            uint_t wv[4];
            #pragma unroll
            for (int i = 0; i < 4; ++i) {
                uint_t A  = Tp[(cc * 8 + 2 * i) * 33 + l2];
                uint_t Bv = Tp[(cc * 8 + 2 * i + 1) * 33 + l2];
                wv[i] = __builtin_amdgcn_perm(Bv, A, sel8);   // (A.sel, B.sel)
            }
            *(uint4*)&Dst[((size_t)((b << 10) + l0 + lr)) * U_ + u0 + cc * 8] = *(uint4*)wv;
        }
    } else if (bid < 8192) {
        // ---- nelmask: per-wave width detect (no shared / atomic / barrier) ----
        const int lane = tid & 63;
        const uint4* m4 = (const uint4*)mask;
        uint4 dw = m4[lane];                 // first 1KB, L2-hot
        bool all4 = (dw.x <= 1u) && (dw.y <= 1u) && (dw.z <= 1u) && (dw.w <= 1u);
        const int isInt = (__popcll(__ballot(all4)) >= 32) ? 1 : 0;

        int row  = (bid - 4096) * 4 + (tid >> 6);   // b*1024 + x
        const uint8_t* m8  = (const uint8_t*)mask + (size_t)row * LY_;
        const int*     m32 = (const int*)mask + (size_t)row * LY_;
        int cnt = 0;
        if (isInt) {
            #pragma unroll 4
            for (int yg = 0; yg < LY_ / 64; ++yg) {
                unsigned long long bal = __ballot(m32[yg * 64 + lane] != 0);
                if (lane == 0) {
                    mb[(size_t)row * 32 + yg * 2]     = (uint_t)bal;
                    mb[(size_t)row * 32 + yg * 2 + 1] = (uint_t)(bal >> 32);
                    cnt += __popcll(bal);
                }
            }
        } else {
            #pragma unroll 4
            for (int yg = 0; yg < LY_ / 64; ++yg) {
                unsigned long long bal = __ballot(m8[yg * 64 + lane] != 0);
                if (lane == 0) {
                    mb[(size_t)row * 32 + yg * 2]     = (uint_t)bal;
                    mb[(size_t)row * 32 + yg * 2 + 1] = (uint_t)(bal >> 32);
                    cnt += __popcll(bal);
                }
            }
        }
        if (lane == 0) nel[row] = (float)(cnt > 0 ? cnt : 1);
    } else {
        // ---- castw ----
        int cb = bid - 8192;                // 0..767
        int selw = cb >> 8;
        const float* sw = selw == 0 ? wq : (selw == 1 ? wk : wo);
        ushort_t*    dw = selw == 0 ? wqb : (selw == 1 ? wkb : wob);
        int i = ((cb & 255) * 256 + tid) * 4;
        float4 v = *(const float4*)&sw[i];
        ushort4 p;
        p.x = bf16u(v.x); p.y = bf16u(v.y); p.z = bf16u(v.z); p.w = bf16u(v.w);
        *(ushort4*)&dw[i] = p;
    }
}

// ---------------------------------------------------------------------------
// Merged Q/K GEMM, one full-device dispatch (1024 blocks).
//   id < 512 : QT[b][x][u]  = xT[b] (M=1024) x wq (N=512)
//   id >= 512: Ka[b][u][y]  = wk (M=512) x yT[b] (N=1024)
//              + dual-write Kb[b][h][y][d] via packed uint2 (8B) stores:
//              each quadrant's r-quads are d-consecutive -> 16 stores/thread
//              (was 64 x 2B scatter -> L2 RMW amplification).
// ---------------------------------------------------------------------------
__global__ __launch_bounds__(256) void gemm_qk(const ushort_t* __restrict__ xT,
                                               const ushort_t* __restrict__ wqb,
                                               const ushort_t* __restrict__ wkb,
                                               const ushort_t* __restrict__ yT,
                                               ushort_t* __restrict__ QT,
                                               ushort_t* __restrict__ Ka,
                                               ushort_t* __restrict__ Kb) {
    __shared__ __align__(16) ushort_t As[128 * 64];
    __shared__ __align__(16) ushort_t Bs[128 * 64];
    const int tid = threadIdx.x;
    const int id  = blockIdx.x;
    const int isK = id >> 9;
    const int lid = id & 511;
    const int b   = lid >> 5;
    int m0, n0, ldOut;
    const ushort_t *Ab, *Bb;
    ushort_t* Ob;
    if (!isK) {
        n0 = (lid & 3) * 128; m0 = ((lid >> 2) & 7) * 128;
        Ab = xT + (size_t)b * (LX_ * U_); Bb = wqb;
        Ob = QT + (size_t)b * (LX_ * U_); ldOut = U_;
    } else {
        n0 = (lid & 7) * 128; m0 = ((lid >> 3) & 3) * 128;
        Ab = wkb; Bb = yT + (size_t)b * (LY_ * U_);
        Ob = Ka + (size_t)b * (U_ * LY_); ldOut = LY_;
    }

    const int w = tid >> 6, lane = tid & 63, lo = lane & 31, hi = lane >> 5;
    const int wm = (w >> 1) * 64, wn = (w & 1) * 64;

    v16f acc00, acc01, acc10, acc11;
    #pragma unroll
    for (int i = 0; i < 16; ++i) { acc00[i] = 0.f; acc01[i] = 0.f; acc10[i] = 0.f; acc11[i] = 0.f; }

    for (int kk = 0; kk < 8; ++kk) {
        const int k0 = kk * 64;
        #pragma unroll
        for (int e = 0; e < 4; ++e) {
            int ci = e * 256 + tid;          // 0..1023 16B chunks
            int r = ci >> 3, c = ci & 7;
            int g = (c ^ (r & 7)) << 3;      // swizzle on SOURCE chunk
            gload16(&Ab[(size_t)(m0 + r) * U_ + k0 + g], &As[ci * 8]);
            gload16(&Bb[(size_t)(n0 + r) * U_ + k0 + g], &Bs[ci * 8]);
        }
        __syncthreads();
        #pragma unroll
        for (int ks = 0; ks < 4; ++ks) {
            int ch = ks * 2 + hi;
            int rA0 = wm + lo, rA1 = wm + 32 + lo;
            int rB0 = wn + lo, rB1 = wn + 32 + lo;
            v8bf a0 = *(v8bf*)&As[rA0 * 64 + ((ch ^ (rA0 & 7)) << 3)];
            v8bf a1 = *(v8bf*)&As[rA1 * 64 + ((ch ^ (rA1 & 7)) << 3)];
            v8bf b0 = *(v8bf*)&Bs[rB0 * 64 + ((ch ^ (rB0 & 7)) << 3)];
            v8bf b1 = *(v8bf*)&Bs[rB1 * 64 + ((ch ^ (rB1 & 7)) << 3)];
            acc00 = __builtin_amdgcn_mfma_f32_32x32x16_bf16(a0, b0, acc00, 0, 0, 0);
            acc01 = __builtin_amdgcn_mfma_f32_32x32x16_bf16(a0, b1, acc01, 0, 0, 0);
            acc10 = __builtin_amdgcn_mfma_f32_32x32x16_bf16(a1, b0, acc10, 0, 0, 0);
            acc11 = __builtin_amdgcn_mfma_f32_32x32x16_bf16(a1, b1, acc11, 0, 0, 0);
        }
        __syncthreads();
    }

    #pragma unroll
    for (int mi = 0; mi < 2; ++mi) {
        #pragma unroll
        for (int nj = 0; nj < 2; ++nj) {
            v16f c = mi ? (nj ? acc11 : acc10) : (nj ? acc01 : acc00);
            int n = n0 + wn + nj * 32 + lo;
            int mbase = m0 + wm + mi * 32;
            ushort_t us[16];
            #pragma unroll
            for (int r = 0; r < 16; ++r) {
                int m = mbase + (r & 3) + 8 * (r >> 2) + 4 * hi;
                ushort_t v = bf16u(c[r]);
                us[r] = v;
                Ob[(size_t)m * ldOut + n] = v;
            }
            if (isK) {
                // quadrant spans ONE head; r-quads are d-consecutive
                int head = mbase >> 6;
                int db   = (mbase & 63) + 4 * hi;
                ushort_t* kbrow = Kb + (((size_t)(b * H_ + head) << 10) + n) * D_ + db;
                #pragma unroll
                for (int q = 0; q < 4; ++q) {
                    uint2 pk2;
                    pk2.x = (uint_t)us[q * 4 + 0] | ((uint_t)us[q * 4 + 1] << 16);
                    pk2.y = (uint_t)us[q * 4 + 2] | ((uint_t)us[q * 4 + 3] << 16);
                    *(uint2*)&kbrow[q * 8] = pk2;
                }
            }
        }
    }
}

// ---------------------------------------------------------------------------
// O-GEMM: Out[b][m][n] = sum_k A[m][k] * B_b[n][k], fp32 out.
// ---------------------------------------------------------------------------
template <int OUTF32>
__global__ __launch_bounds__(256) void gemm_mfma(const ushort_t* __restrict__ A, size_t aStr,
                                                 const ushort_t* __restrict__ Bm, size_t bStr,
                                                 void* __restrict__ Out, size_t oStr, int ldOut) {
    const int n0 = blockIdx.x * 128;
    const int m0 = blockIdx.y * 128;
    const int b  = blockIdx.z;
    __shared__ __align__(16) ushort_t As[128 * 64];
    __shared__ __align__(16) ushort_t Bs[128 * 64];
    const int tid = threadIdx.x;
    const ushort_t* Ab = A + aStr * b;
    const ushort_t* Bb = Bm + bStr * b;

    const int w = tid >> 6, lane = tid & 63, lo = lane & 31, hi = lane >> 5;
    const int wm = (w >> 1) * 64, wn = (w & 1) * 64;

    v16f acc00, acc01, acc10, acc11;
    #pragma unroll
    for (int i = 0; i < 16; ++i) { acc00[i] = 0.f; acc01[i] = 0.f; acc10[i] = 0.f; acc11[i] = 0.f; }

    for (int kk = 0; kk < 8; ++kk) {
        const int k0 = kk * 64;
        #pragma unroll
        for (int e = 0; e < 4; ++e) {
            int ci = e * 256 + tid;          // 0..1023 16B chunks
            int r = ci >> 3, c = ci & 7;
            int g = (c ^ (r & 7)) << 3;      // swizzle on SOURCE chunk
            gload16(&Ab[(size_t)(m0 + r) * U_ + k0 + g], &As[ci * 8]);
            gload16(&Bb[(size_t)(n0 + r) * U_ + k0 + g], &Bs[ci * 8]);
        }
        __syncthreads();
        #pragma unroll
        for (int ks = 0; ks < 4; ++ks) {
            int ch = ks * 2 + hi;
            int rA0 = wm + lo, rA1 = wm + 32 + lo;
            int rB0 = wn + lo, rB1 = wn + 32 + lo;
            v8bf a0 = *(v8bf*)&As[rA0 * 64 + ((ch ^ (rA0 & 7)) << 3)];
            v8bf a1 = *(v8bf*)&As[rA1 * 64 + ((ch ^ (rA1 & 7)) << 3)];
            v8bf b0 = *(v8bf*)&Bs[rB0 * 64 + ((ch ^ (rB0 & 7)) << 3)];
            v8bf b1 = *(v8bf*)&Bs[rB1 * 64 + ((ch ^ (rB1 & 7)) << 3)];
            acc00 = __builtin_amdgcn_mfma_f32_32x32x16_bf16(a0, b0, acc00, 0, 0, 0);
            acc01 = __builtin_amdgcn_mfma_f32_32x32x16_bf16(a0, b1, acc01, 0, 0, 0);
            acc10 = __builtin_amdgcn_mfma_f32_32x32x16_bf16(a1, b0, acc10, 0, 0, 0);
            acc11 = __builtin_amdgcn_mfma_f32_32x32x16_bf16(a1, b1, acc11, 0, 0, 0);
        }
        __syncthreads();
    }

    #pragma unroll
    for (int mi = 0; mi < 2; ++mi) {
        #pragma unroll
        for (int nj = 0; nj < 2; ++nj) {
            v16f c = mi ? (nj ? acc11 : acc10) : (nj ? acc01 : acc00);
            int n = n0 + wn + nj * 32 + lo;
            #pragma unroll
            for (int r = 0; r < 16; ++r) {
                int m = m0 + wm + mi * 32 + (r & 3) + 8 * (r >> 2) + 4 * hi;
                size_t addr = oStr * b + (size_t)m * ldOut + n;
                if (OUTF32) ((float*)Out)[addr] = c[r];
                else        ((ushort_t*)Out)[addr] = bf16u(c[r]);
            }
        }
    }
}

// ---------------------------------------------------------------------------
// Fused bf16-MFMA attention, 4-way x-split, in-register S->C handoff, 32 KB.
// (R3 structure: VGPR=60, no spill, 4 blocks/CU; tt-loop unrolled x2 so the
// buffer-parity addressing is compile-time constant)
// ---------------------------------------------------------------------------
typedef uint_t v2u __attribute__((ext_vector_type(2)));

// s: 16 f32 of one 32x32 S^T block (D-layout, cols = this lane's x). wbh:
// mask word for the block's 32 y's >> (hi*8).  fr[t]: B-operand fragment for
// k-step t (t=0: y_off 0..15, t=1: 16..31 relative to the block).
__device__ __forceinline__ void conv_sblock(const v16f& s, uint_t wbh, v8bf* fr) {
    uint_t pk[8];
    #pragma unroll
    for (int i = 0; i < 8; ++i) {
        float f0 = fmaxf(s[2 * i + 0], 0.f);
        float f1 = fmaxf(s[2 * i + 1], 0.f);
        uint_t r;
        asm("v_cvt_pk_bf16_f32 %0, %1, %2" : "=v"(r) : "v"(f0), "v"(f1));
        pk[i] = r;
    }
    #pragma unroll
    for (int t = 0; t < 2; ++t) {
        // swap(A,B): A'[32+i]=B[i], B'[i]=A[32+i]
        auto ra = __builtin_amdgcn_permlane32_swap(pk[4 * t + 0], pk[4 * t + 2], false, false);
        auto rb = __builtin_amdgcn_permlane32_swap(pk[4 * t + 1], pk[4 * t + 3], false, false);
        uint_t w0 = ra[0];   // j={0,1}:  y_off = t*16 + hi*8 + {0,1}
        uint_t w1 = rb[0];   // j={2,3}
        uint_t w2 = ra[1];   // j={4,5}
        uint_t w3 = rb[1];   // j={6,7}
        uint_t u0 = wbh >> (t * 16 + 0);
        uint_t u1 = wbh >> (t * 16 + 2);
        uint_t u2 = wbh >> (t * 16 + 4);
        uint_t u3 = wbh >> (t * 16 + 6);
        w0 &= ((u0 & 1u) * 0xFFFFu) | ((u0 & 2u) * 0x7FFF8000u);
        w1 &= ((u1 & 1u) * 0xFFFFu) | ((u1 & 2u) * 0x7FFF8000u);
        w2 &= ((u2 & 1u) * 0xFFFFu) | ((u2 & 2u) * 0x7FFF8000u);
        w3 &= ((u3 & 1u) * 0xFFFFu) | ((u3 & 2u) * 0x7FFF8000u);
        union { uint_t u[4]; v8bf b; } cv;
        cv.u[0] = w0; cv.u[1] = w1; cv.u[2] = w2; cv.u[3] = w3;
        fr[t] = cv.b;
    }
}

__global__ __launch_bounds__(256, 4) void attn_mfma(const ushort_t* __restrict__ QTg,
                                                    const ushort_t* __restrict__ Ka_g,
                                                    const ushort_t* __restrict__ Kb_g,
                                                    const uint_t* __restrict__ mbits,
                                                    const float* __restrict__ nel,
                                                    ushort_t* __restrict__ ETg) {
    const int tid = threadIdx.x;
    const int id  = blockIdx.x;
    const int bh  = id & 127;          // same-bh blocks -> same XCD (id%8 heuristic)
    const int x0g = (id >> 7) * 128;
    const int b = bh >> 3, h = bh & 7;

    // 32 KB: KB dbuf [0,16KB) | KA dbuf [16KB,32KB).  Reused post-loop as Et.
    __shared__ __align__(16) ushort_t SM[4 * 4096];

    const int w    = tid >> 6;         // x-quarter index 0..3
    const int lane = tid & 63;
    const int lo   = lane & 31;
    const int hi   = lane >> 5;
    const int xq   = w * 32;           // x-quarter base within the 128-x tile

    const ushort_t* KaBase = Ka_g + ((size_t)(b * U_ + h * D_)) * LY_;
    const ushort_t* KbBase = Kb_g + ((size_t)(b * H_ + h)) * LY_ * D_;
    const int bx = b * LX_ + x0g;
    const int xg = bx + xq + lo;       // this lane's global x row

    // ---- stage first K tile into buffer 0 ----
    #pragma unroll
    for (int e = 0; e < 2; ++e) {
        int ci = e * 256 + tid;
        int r = ci >> 3, c = ci & 7;
        int g8 = (c ^ (r & 7)) << 3;
        gload16(&KbBase[(size_t)r * D_ + g8], &SM[ci * 8]);
        gload16(&KaBase[(size_t)r * LY_ + g8], &SM[8192 + ci * 8]);
    }

    // ---- Q B-fragments straight from global (loop-invariant, 16 VGPR) ----
    v8bf qf[4];
    {
        const ushort_t* q0 = QTg + (size_t)xg * U_ + h * D_;
        #pragma unroll
        for (int kt = 0; kt < 4; ++kt) qf[kt] = *(const v8bf*)&q0[(kt * 2 + hi) * 8];
    }

    // full-C accumulators for this x-quarter: acc0 = d 0..31, acc1 = d 32..63
    v16f acc0, acc1;
    #pragma unroll
    for (int i = 0; i < 16; ++i) { acc0[i] = 0.f; acc1[i] = 0.f; }

    __syncthreads();   // first tile staged (drains gload_lds)

    #pragma unroll 2
    for (int tt = 0; tt < 16; ++tt) {
        ushort_t* KBc = SM + (tt & 1) * 4096;
        ushort_t* KAc = SM + 8192 + (tt & 1) * 4096;

        // prefetch next tile into other buffer; drained by end-of-tile barrier
        if (tt < 15) {
            ushort_t* KBn = SM + ((tt + 1) & 1) * 4096;
            ushort_t* KAn = SM + 8192 + ((tt + 1) & 1) * 4096;
            const int yn = tt * 64 + 64;
            #pragma unroll
            for (int e = 0; e < 2; ++e) {
                int ci = e * 256 + tid;
                int r = ci >> 3, c = ci & 7;
                int g8 = (c ^ (r & 7)) << 3;
                gload16(&KbBase[(size_t)(yn + r) * D_ + g8], &KBn[ci * 8]);
                gload16(&KaBase[(size_t)r * LY_ + yn + g8], &KAn[ci * 8]);
            }
        }
        // both 32-y mask words for this lane's x row, one 8B load
        v2u wb = *(const v2u*)&mbits[(size_t)xg * 32 + tt * 2];

        // ---- S-phase, y-block 0 (y0..y0+31): S^T = Kb * Q^T ----
        v8bf fr0[2], fr1[2];
        {
            v16f s;
            #pragma unroll
            for (int i = 0; i < 16; ++i) s[i] = 0.f;
            #pragma unroll
            for (int kt = 0; kt < 4; ++kt) {
                int ch = kt * 2 + hi;
                v8bf a = *(v8bf*)&KBc[lo * 64 + ((ch ^ (lo & 7)) << 3)];
                s = __builtin_amdgcn_mfma_f32_32x32x16_bf16(a, qf[kt], s, 0, 0, 0);
            }
            conv_sblock(s, wb[0] >> (hi * 8), fr0);
        }
        // ---- S-phase, y-block 1 (y0+32..y0+63) ----
        {
            v16f s;
            #pragma unroll
            for (int i = 0; i < 16; ++i) s[i] = 0.f;
            #pragma unroll
            for (int kt = 0; kt < 4; ++kt) {
                int ch = kt * 2 + hi;
                v8bf a = *(v8bf*)&KBc[(32 + lo) * 64 + ((ch ^ ((32 + lo) & 7)) << 3)];
                s = __builtin_amdgcn_mfma_f32_32x32x16_bf16(a, qf[kt], s, 0, 0, 0);
            }
            conv_sblock(s, wb[1] >> (hi * 8), fr1);
        }

        // ---- C-phase: C[d][x-quarter] += Ka * S over all 64 y ----
        #pragma unroll
        for (int kt = 0; kt < 4; ++kt) {
            int ch = kt * 2 + hi;
            v8bf frk = (kt < 2) ? fr0[kt] : fr1[kt - 2];
            v8bf a0 = *(v8bf*)&KAc[lo * 64 + ((ch ^ (lo & 7)) << 3)];
            v8bf a1 = *(v8bf*)&KAc[(32 + lo) * 64 + ((ch ^ ((32 + lo) & 7)) << 3)];
            acc0 = __builtin_amdgcn_mfma_f32_32x32x16_bf16(a0, frk, acc0, 0, 0, 0);
            acc1 = __builtin_amdgcn_mfma_f32_32x32x16_bf16(a1, frk, acc1, 0, 0, 0);
        }
        __syncthreads();   // drains prefetch vmcnt + protects buffer swap
    }

    // ---- epilogue: E = 0.5*Q + C*(0.0625/nel) -> Et (dead K region) ----
    // Wave owns full C for its x-quarter; no cross-wave reduction needed.
    {
        ushort_t* Et = SM;
        const int xl = xq + lo;
        float invn = 0.0625f / nel[xg];
        const ushort_t* qg = QTg + (size_t)xg * U_ + h * D_ + 4 * hi;
        #pragma unroll
        for (int half = 0; half < 2; ++half) {
            const v16f& c = half ? acc1 : acc0;
            #pragma unroll
            for (int q = 0; q < 4; ++q) {
                int d0 = half * 32 + q * 8 + 4 * hi;               // d0&7 == 4*hi
                ushort_t q4[4];
                *(uint2*)q4 = *(const uint2*)&qg[half * 32 + q * 8];
                ushort_t e4[4];
                e4[0] = bf16u(0.5f * bfu2f(q4[0]) + c[q * 4 + 0] * invn);
                e4[1] = bf16u(0.5f * bfu2f(q4[1]) + c[q * 4 + 1] * invn);
                e4[2] = bf16u(0.5f * bfu2f(q4[2]) + c[q * 4 + 2] * invn);
                e4[3] = bf16u(0.5f * bfu2f(q4[3]) + c[q * 4 + 3] * invn);
                int base = xl * 64 + ((((d0 >> 3) ^ (xl & 7)) << 3) | (4 * hi));
                *(uint2*)&Et[base] = *(uint2*)e4;
            }
        }
    }
    __syncthreads();
    // ---- write ET[b][x][h*64+d] coalesced (un-swizzle on read) ----
    #pragma unroll
    for (int e = 0; e < 4; ++e) {
        int idx = e * 256 + tid;
        int row = idx >> 3, cc = idx & 7;
        uint4 v = *(const uint4*)&SM[row * 64 + ((cc ^ (row & 7)) << 3)];
        *(uint4*)&ETg[((size_t)(bx + row)) * U_ + h * D_ + cc * 8] = v;
    }
}

// ---------------------------------------------------------------------------
extern "C" void kernel_launch(void* const* d_in, const int* in_sizes, int n_in,
                              void* d_out, int out_size, void* d_ws, size_t ws_size,
                              hipStream_t stream) {
    const float* x    = (const float*)d_in[0];
    const float* y    = (const float*)d_in[1];
    const void*  mask = d_in[2];
    const float* wq   = (const float*)d_in[3];
    const float* wk   = (const float*)d_in[4];
    const float* wo   = (const float*)d_in[5];

    // ws layout (bytes):
    //   [0,        16777216)  xT bf16   -> later ET bf16
    //   [16777216, 33554432)  yT bf16
    //   [33554432, 50331648)  Ka bf16
    //   [50331648, 50855936)  wq bf16
    //   [50855936, 51380224)  wk bf16
    //   [51380224, 51904512)  wo bf16
    //   [51904512, 54001664)  maskBits u32
    //   [54001664, 54067200)  nel f32
    // d_out (33.5 MB fp32) moonlights as: QT bf16 [0,16MB) | Kb bf16 [16MB,32MB)
    // until the O-GEMM overwrites it.
    char* wsb = (char*)d_ws;
    ushort_t* xT    = (ushort_t*)(wsb);
    ushort_t* yT    = (ushort_t*)(wsb + 16777216);
    ushort_t* Ka    = (ushort_t*)(wsb + 33554432);
    ushort_t* wqb   = (ushort_t*)(wsb + 50331648);
    ushort_t* wkb   = (ushort_t*)(wsb + 50855936);
    ushort_t* wob   = (ushort_t*)(wsb + 51380224);
    uint_t*   mbits = (uint_t*)(wsb + 51904512);
    float*    nel   = (float*)(wsb + 54001664);
    ushort_t* ET    = xT;                 // alias: xT dead after Q-GEMM
    ushort_t* QT    = (ushort_t*)d_out;                         // [0, 16MB)
    ushort_t* Kb    = (ushort_t*)d_out + (size_t)B_ * LX_ * U_; // [16MB, 32MB)

    prep_kernel<<<8960, 256, 0, stream>>>(x, y, mask, wq, wk, wo,
                                          xT, yT, wqb, wkb, wob, nel, mbits);
    gemm_qk<<<1024, 256, 0, stream>>>(xT, wqb, wkb, yT, QT, Ka, Kb);
    attn_mfma<<<1024, 256, 0, stream>>>(QT, Ka, Kb, mbits, nel, ET);
    // out[b][u][x] fp32 = wo (M=512) x ET[b] (N=1024)
    gemm_mfma<1><<<dim3(8, 4, B_), 256, 0, stream>>>(
        wob, 0, ET, (size_t)LX_ * U_, d_out, (size_t)U_ * LX_, LX_);
}

// Round 6
// 264.044 us; speedup vs baseline: 1.0921x; 1.0576x over previous
//
#include <hip/hip_runtime.h>
#include <stdint.h>
#include <stddef.h>

#define B_  16
#define U_  512
#define LX_ 1024
#define LY_ 1024
#define H_  8
#define D_  64

typedef unsigned short ushort_t;
typedef unsigned int   uint_t;
typedef __bf16 v8bf  __attribute__((ext_vector_type(8)));
typedef float  v16f  __attribute__((ext_vector_type(16)));

__device__ __forceinline__ ushort_t bf16u(float f) {
    uint_t u = __float_as_uint(f);
    uint_t r = (u + 0x7FFFu + ((u >> 16) & 1u)) >> 16;
    return (ushort_t)r;
}
__device__ __forceinline__ float bfu2f(ushort_t u) {
    return __uint_as_float(((uint_t)u) << 16);
}
// RNE-pack two fp32 -> packed bf16x2 (low=f0) using v_perm_b32.
__device__ __forceinline__ uint_t pkbf16(float f0, float f1) {
    uint_t u0 = __float_as_uint(f0), u1 = __float_as_uint(f1);
    u0 = u0 + 0x7FFFu + ((u0 >> 16) & 1u);
    u1 = u1 + 0x7FFFu + ((u1 >> 16) & 1u);
    return __builtin_amdgcn_perm(u1, u0, 0x07060302u);
}
// async global->LDS, 16B/lane. LDS dest is wave-uniform base + lane*16, so
// swizzling must be applied to the GLOBAL source chunk, not the LDS address.
__device__ __forceinline__ void gload16(const void* g, void* l) {
    auto gp = (const __attribute__((address_space(1))) uint32_t*)(uintptr_t)g;
    auto lp = (__attribute__((address_space(3))) uint32_t*)(uintptr_t)l;
    __builtin_amdgcn_global_load_lds(gp, lp, 16, 0, 0);
}

// ---------------------------------------------------------------------------
// castT v3: x,y [b][u][l] f32 -> [b][l][u] bf16.  64x64 tiles.
// Phase 1: async gload16 of the f32 tile with source-chunk swizzle
//          c ^= (r>>3)&7  (bijective per row; zero VALU, zero reg traffic).
// Phase 2: column reads straight from LDS -- addr u*64 + ((l>>2)^(u>>3))*4 +
//          (l&3): per read-instr banks spread 2-way (free), then pkbf16 and
//          one coalesced 16B store per octet.
// ---------------------------------------------------------------------------
__global__ __launch_bounds__(256) void castT_kernel(const float* __restrict__ X,
                                                    const float* __restrict__ Y,
                                                    ushort_t* __restrict__ XT,
                                                    ushort_t* __restrict__ YT) {
    __shared__ __align__(16) float Tf[64 * 64];
    const int tid = threadIdx.x;
    const int bid = blockIdx.x;
    const int l0 = (bid & 15) * 64;
    const int u0 = ((bid >> 4) & 7) * 64;
    const int z  = bid >> 7;            // 0..31
    const int b  = z & 15;
    const int sel = z >> 4;
    const float* S = sel ? Y : X;
    ushort_t*  Dst = sel ? YT : XT;

    #pragma unroll
    for (int e = 0; e < 4; ++e) {
        int ci = e * 256 + tid;          // 0..1023 16B chunks
        int r = ci >> 4, c = ci & 15;
        int g = (c ^ ((r >> 3) & 7)) << 2;   // swizzled float offset in row
        gload16(&S[((size_t)(b * U_ + u0 + r) << 10) + l0 + g], &Tf[ci * 4]);
    }
    __syncthreads();
    #pragma unroll
    for (int e = 0; e < 2; ++e) {
        int idx = e * 256 + tid;         // 0..511: (l-row, u-octet)
        int lr = idx >> 3, uo = idx & 7;
        float f[8];
        #pragma unroll
        for (int k = 0; k < 8; ++k) {
            int u = uo * 8 + k;
            int c = (lr >> 2) ^ uo;      // (u>>3)&7 == uo
            f[k] = Tf[u * 64 + c * 4 + (lr & 3)];
        }
        uint_t wv[4];
        #pragma unroll
        for (int j = 0; j < 4; ++j) wv[j] = pkbf16(f[2 * j], f[2 * j + 1]);
        *(uint4*)&Dst[((size_t)((b << 10) + l0 + lr)) * U_ + u0 + uo * 8] = *(uint4*)wv;
    }
}

// ---------------------------------------------------------------------------
// nelmask v3 + castw, blockIdx-partitioned.
//   [0, 4096): one wave = one mask row.  Each lane owns 16 y's, loads them
//              as uint4 (bool: 1 load; int32: 4 loads), builds a 16-bit
//              presence mask IN REGISTERS (no load->ballot chains), pairs
//              combine via shfl_xor, 32 contiguous word stores per row.
//   [4096, 4864): castw -- wq/wk/wo f32 -> bf16.
// ---------------------------------------------------------------------------
__global__ __launch_bounds__(256) void nelw_kernel(const void* __restrict__ mask,
                                                   const float* __restrict__ wq,
                                                   const float* __restrict__ wk,
                                                   const float* __restrict__ wo,
                                                   ushort_t* __restrict__ wqb,
                                                   ushort_t* __restrict__ wkb,
                                                   ushort_t* __restrict__ wob,
                                                   float* __restrict__ nel,
                                                   uint_t* __restrict__ mb) {
    const int tid = threadIdx.x;
    const int bid = blockIdx.x;
    if (bid < 4096) {
        const int lane = tid & 63;
        // width detect: first 1KB of mask (L2-hot), per-wave, no barriers
        uint4 dw = ((const uint4*)mask)[lane];
        bool all4 = (dw.x <= 1u) && (dw.y <= 1u) && (dw.z <= 1u) && (dw.w <= 1u);
        const int isInt = (__popcll(__ballot(all4)) >= 32) ? 1 : 0;

        const int row = bid * 4 + (tid >> 6);       // b*1024 + x
        uint_t m16 = 0;
        if (isInt) {
            const uint4* mr = (const uint4*)((const int*)mask + (size_t)row * LY_);
            #pragma unroll
            for (int i = 0; i < 4; ++i) {
                uint4 v = mr[lane * 4 + i];          // dwords [16*lane+4i, +4)
                uint_t m4 = (v.x != 0 ? 1u : 0u) | (v.y != 0 ? 2u : 0u)
                          | (v.z != 0 ? 4u : 0u) | (v.w != 0 ? 8u : 0u);
                m16 |= m4 << (4 * i);
            }
        } else {
            const uint4* mr = (const uint4*)((const uint8_t*)mask + (size_t)row * LY_);
            uint4 v = mr[lane];                      // bytes [16*lane, +16)
            uint_t d[4] = {v.x, v.y, v.z, v.w};
            #pragma unroll
            for (int i = 0; i < 4; ++i) {
                uint_t u = d[i];
                uint_t nz = (u | ((u & 0x7F7F7F7Fu) + 0x7F7F7F7Fu)) & 0x80808080u;
                uint_t m4 = ((nz >> 7) & 1u) | ((nz >> 14) & 2u)
                          | ((nz >> 21) & 4u) | ((nz >> 28) & 8u);
                m16 |= m4 << (4 * i);
            }
        }
        uint_t other = (uint_t)__shfl_xor((int)m16, 1);
        if ((lane & 1) == 0)
            mb[(size_t)row * 32 + (lane >> 1)] = m16 | (other << 16);
        int cnt = __popc(m16);
        #pragma unroll
        for (int o = 1; o < 64; o <<= 1) cnt += __shfl_xor(cnt, o);
        if (lane == 0) nel[row] = (float)(cnt > 0 ? cnt : 1);
    } else {
        // ---- castw ----
        int cb = bid - 4096;                // 0..767
        int selw = cb >> 8;
        const float* sw = selw == 0 ? wq : (selw == 1 ? wk : wo);
        ushort_t*    dw = selw == 0 ? wqb : (selw == 1 ? wkb : wob);
        int i = ((cb & 255) * 256 + tid) * 4;
        float4 v = *(const float4*)&sw[i];
        ushort4 p;
        p.x = bf16u(v.x); p.y = bf16u(v.y); p.z = bf16u(v.z); p.w = bf16u(v.w);
        *(ushort4*)&dw[i] = p;
    }
}

// ---------------------------------------------------------------------------
// Merged Q/K GEMM, one full-device dispatch (1024 blocks).
//   id < 512 : QT[b][x][u]  = xT[b] (M=1024) x wq (N=512)
//   id >= 512: Ka[b][u][y]  = wk (M=512) x yT[b] (N=1024)
//              + dual-write Kb[b][h][y][d] via packed uint2 (8B) stores.
// ---------------------------------------------------------------------------
__global__ __launch_bounds__(256) void gemm_qk(const ushort_t* __restrict__ xT,
                                               const ushort_t* __restrict__ wqb,
                                               const ushort_t* __restrict__ wkb,
                                               const ushort_t* __restrict__ yT,
                                               ushort_t* __restrict__ QT,
                                               ushort_t* __restrict__ Ka,
                                               ushort_t* __restrict__ Kb) {
    __shared__ __align__(16) ushort_t As[128 * 64];
    __shared__ __align__(16) ushort_t Bs[128 * 64];
    const int tid = threadIdx.x;
    const int id  = blockIdx.x;
    const int isK = id >> 9;
    const int lid = id & 511;
    const int b   = lid >> 5;
    int m0, n0, ldOut;
    const ushort_t *Ab, *Bb;
    ushort_t* Ob;
    if (!isK) {
        n0 = (lid & 3) * 128; m0 = ((lid >> 2) & 7) * 128;
        Ab = xT + (size_t)b * (LX_ * U_); Bb = wqb;
        Ob = QT + (size_t)b * (LX_ * U_); ldOut = U_;
    } else {
        n0 = (lid & 7) * 128; m0 = ((lid >> 3) & 3) * 128;
        Ab = wkb; Bb = yT + (size_t)b * (LY_ * U_);
        Ob = Ka + (size_t)b * (U_ * LY_); ldOut = LY_;
    }

    const int w = tid >> 6, lane = tid & 63, lo = lane & 31, hi = lane >> 5;
    const int wm = (w >> 1) * 64, wn = (w & 1) * 64;

    v16f acc00, acc01, acc10, acc11;
    #pragma unroll
    for (int i = 0; i < 16; ++i) { acc00[i] = 0.f; acc01[i] = 0.f; acc10[i] = 0.f; acc11[i] = 0.f; }

    for (int kk = 0; kk < 8; ++kk) {
        const int k0 = kk * 64;
        #pragma unroll
        for (int e = 0; e < 4; ++e) {
            int ci = e * 256 + tid;          // 0..1023 16B chunks
            int r = ci >> 3, c = ci & 7;
            int g = (c ^ (r & 7)) << 3;      // swizzle on SOURCE chunk
            gload16(&Ab[(size_t)(m0 + r) * U_ + k0 + g], &As[ci * 8]);
            gload16(&Bb[(size_t)(n0 + r) * U_ + k0 + g], &Bs[ci * 8]);
        }
        __syncthreads();
        #pragma unroll
        for (int ks = 0; ks < 4; ++ks) {
            int ch = ks * 2 + hi;
            int rA0 = wm + lo, rA1 = wm + 32 + lo;
            int rB0 = wn + lo, rB1 = wn + 32 + lo;
            v8bf a0 = *(v8bf*)&As[rA0 * 64 + ((ch ^ (rA0 & 7)) << 3)];
            v8bf a1 = *(v8bf*)&As[rA1 * 64 + ((ch ^ (rA1 & 7)) << 3)];
            v8bf b0 = *(v8bf*)&Bs[rB0 * 64 + ((ch ^ (rB0 & 7)) << 3)];
            v8bf b1 = *(v8bf*)&Bs[rB1 * 64 + ((ch ^ (rB1 & 7)) << 3)];
            acc00 = __builtin_amdgcn_mfma_f32_32x32x16_bf16(a0, b0, acc00, 0, 0, 0);
            acc01 = __builtin_amdgcn_mfma_f32_32x32x16_bf16(a0, b1, acc01, 0, 0, 0);
            acc10 = __builtin_amdgcn_mfma_f32_32x32x16_bf16(a1, b0, acc10, 0, 0, 0);
            acc11 = __builtin_amdgcn_mfma_f32_32x32x16_bf16(a1, b1, acc11, 0, 0, 0);
        }
        __syncthreads();
    }

    #pragma unroll
    for (int mi = 0; mi < 2; ++mi) {
        #pragma unroll
        for (int nj = 0; nj < 2; ++nj) {
            v16f c = mi ? (nj ? acc11 : acc10) : (nj ? acc01 : acc00);
            int n = n0 + wn + nj * 32 + lo;
            int mbase = m0 + wm + mi * 32;
            ushort_t us[16];
            #pragma unroll
            for (int r = 0; r < 16; ++r) {
                int m = mbase + (r & 3) + 8 * (r >> 2) + 4 * hi;
                ushort_t v = bf16u(c[r]);
                us[r] = v;
                Ob[(size_t)m * ldOut + n] = v;
            }
            if (isK) {
                int head = mbase >> 6;
                int db   = (mbase & 63) + 4 * hi;
                ushort_t* kbrow = Kb + (((size_t)(b * H_ + head) << 10) + n) * D_ + db;
                #pragma unroll
                for (int q = 0; q < 4; ++q) {
                    uint2 pk2;
                    pk2.x = (uint_t)us[q * 4 + 0] | ((uint_t)us[q * 4 + 1] << 16);
                    pk2.y = (uint_t)us[q * 4 + 2] | ((uint_t)us[q * 4 + 3] << 16);
                    *(uint2*)&kbrow[q * 8] = pk2;
                }
            }
        }
    }
}

// ---------------------------------------------------------------------------
// O-GEMM: Out[b][m][n] = sum_k A[m][k] * B_b[n][k], fp32 out.
// ---------------------------------------------------------------------------
template <int OUTF32>
__global__ __launch_bounds__(256) void gemm_mfma(const ushort_t* __restrict__ A, size_t aStr,
                                                 const ushort_t* __restrict__ Bm, size_t bStr,
                                                 void* __restrict__ Out, size_t oStr, int ldOut) {
    const int n0 = blockIdx.x * 128;
    const int m0 = blockIdx.y * 128;
    const int b  = blockIdx.z;
    __shared__ __align__(16) ushort_t As[128 * 64];
    __shared__ __align__(16) ushort_t Bs[128 * 64];
    const int tid = threadIdx.x;
    const ushort_t* Ab = A + aStr * b;
    const ushort_t* Bb = Bm + bStr * b;

    const int w = tid >> 6, lane = tid & 63, lo = lane & 31, hi = lane >> 5;
    const int wm = (w >> 1) * 64, wn = (w & 1) * 64;

    v16f acc00, acc01, acc10, acc11;
    #pragma unroll
    for (int i = 0; i < 16; ++i) { acc00[i] = 0.f; acc01[i] = 0.f; acc10[i] = 0.f; acc11[i] = 0.f; }

    for (int kk = 0; kk < 8; ++kk) {
        const int k0 = kk * 64;
        #pragma unroll
        for (int e = 0; e < 4; ++e) {
            int ci = e * 256 + tid;          // 0..1023 16B chunks
            int r = ci >> 3, c = ci & 7;
            int g = (c ^ (r & 7)) << 3;      // swizzle on SOURCE chunk
            gload16(&Ab[(size_t)(m0 + r) * U_ + k0 + g], &As[ci * 8]);
            gload16(&Bb[(size_t)(n0 + r) * U_ + k0 + g], &Bs[ci * 8]);
        }
        __syncthreads();
        #pragma unroll
        for (int ks = 0; ks < 4; ++ks) {
            int ch = ks * 2 + hi;
            int rA0 = wm + lo, rA1 = wm + 32 + lo;
            int rB0 = wn + lo, rB1 = wn + 32 + lo;
            v8bf a0 = *(v8bf*)&As[rA0 * 64 + ((ch ^ (rA0 & 7)) << 3)];
            v8bf a1 = *(v8bf*)&As[rA1 * 64 + ((ch ^ (rA1 & 7)) << 3)];
            v8bf b0 = *(v8bf*)&Bs[rB0 * 64 + ((ch ^ (rB0 & 7)) << 3)];
            v8bf b1 = *(v8bf*)&Bs[rB1 * 64 + ((ch ^ (rB1 & 7)) << 3)];
            acc00 = __builtin_amdgcn_mfma_f32_32x32x16_bf16(a0, b0, acc00, 0, 0, 0);
            acc01 = __builtin_amdgcn_mfma_f32_32x32x16_bf16(a0, b1, acc01, 0, 0, 0);
            acc10 = __builtin_amdgcn_mfma_f32_32x32x16_bf16(a1, b0, acc10, 0, 0, 0);
            acc11 = __builtin_amdgcn_mfma_f32_32x32x16_bf16(a1, b1, acc11, 0, 0, 0);
        }
        __syncthreads();
    }

    #pragma unroll
    for (int mi = 0; mi < 2; ++mi) {
        #pragma unroll
        for (int nj = 0; nj < 2; ++nj) {
            v16f c = mi ? (nj ? acc11 : acc10) : (nj ? acc01 : acc00);
            int n = n0 + wn + nj * 32 + lo;
            #pragma unroll
            for (int r = 0; r < 16; ++r) {
                int m = m0 + wm + mi * 32 + (r & 3) + 8 * (r >> 2) + 4 * hi;
                size_t addr = oStr * b + (size_t)m * ldOut + n;
                if (OUTF32) ((float*)Out)[addr] = c[r];
                else        ((ushort_t*)Out)[addr] = bf16u(c[r]);
            }
        }
    }
}

// ---------------------------------------------------------------------------
// Fused bf16-MFMA attention, 4-way x-split, in-register S->C handoff, 32 KB.
// (R3 structure: VGPR=60, no spill, 4 blocks/CU; tt-loop unrolled x2)
// ---------------------------------------------------------------------------
typedef uint_t v2u __attribute__((ext_vector_type(2)));

__device__ __forceinline__ void conv_sblock(const v16f& s, uint_t wbh, v8bf* fr) {
    uint_t pk[8];
    #pragma unroll
    for (int i = 0; i < 8; ++i) {
        float f0 = fmaxf(s[2 * i + 0], 0.f);
        float f1 = fmaxf(s[2 * i + 1], 0.f);
        uint_t r;
        asm("v_cvt_pk_bf16_f32 %0, %1, %2" : "=v"(r) : "v"(f0), "v"(f1));
        pk[i] = r;
    }
    #pragma unroll
    for (int t = 0; t < 2; ++t) {
        auto ra = __builtin_amdgcn_permlane32_swap(pk[4 * t + 0], pk[4 * t + 2], false, false);
        auto rb = __builtin_amdgcn_permlane32_swap(pk[4 * t + 1], pk[4 * t + 3], false, false);
        uint_t w0 = ra[0];
        uint_t w1 = rb[0];
        uint_t w2 = ra[1];
        uint_t w3 = rb[1];
        uint_t u0 = wbh >> (t * 16 + 0);
        uint_t u1 = wbh >> (t * 16 + 2);
        uint_t u2 = wbh >> (t * 16 + 4);
        uint_t u3 = wbh >> (t * 16 + 6);
        w0 &= ((u0 & 1u) * 0xFFFFu) | ((u0 & 2u) * 0x7FFF8000u);
        w1 &= ((u1 & 1u) * 0xFFFFu) | ((u1 & 2u) * 0x7FFF8000u);
        w2 &= ((u2 & 1u) * 0xFFFFu) | ((u2 & 2u) * 0x7FFF8000u);
        w3 &= ((u3 & 1u) * 0xFFFFu) | ((u3 & 2u) * 0x7FFF8000u);
        union { uint_t u[4]; v8bf b; } cv;
        cv.u[0] = w0; cv.u[1] = w1; cv.u[2] = w2; cv.u[3] = w3;
        fr[t] = cv.b;
    }
}

__global__ __launch_bounds__(256, 4) void attn_mfma(const ushort_t* __restrict__ QTg,
                                                    const ushort_t* __restrict__ Ka_g,
                                                    const ushort_t* __restrict__ Kb_g,
                                                    const uint_t* __restrict__ mbits,
                                                    const float* __restrict__ nel,
                                                    ushort_t* __restrict__ ETg) {
    const int tid = threadIdx.x;
    const int id  = blockIdx.x;
    const int bh  = id & 127;
    const int x0g = (id >> 7) * 128;
    const int b = bh >> 3, h = bh & 7;

    __shared__ __align__(16) ushort_t SM[4 * 4096];

    const int w    = tid >> 6;
    const int lane = tid & 63;
    const int lo   = lane & 31;
    const int hi   = lane >> 5;
    const int xq   = w * 32;

    const ushort_t* KaBase = Ka_g + ((size_t)(b * U_ + h * D_)) * LY_;
    const ushort_t* KbBase = Kb_g + ((size_t)(b * H_ + h)) * LY_ * D_;
    const int bx = b * LX_ + x0g;
    const int xg = bx + xq + lo;

    #pragma unroll
    for (int e = 0; e < 2; ++e) {
        int ci = e * 256 + tid;
        int r = ci >> 3, c = ci & 7;
        int g8 = (c ^ (r & 7)) << 3;
        gload16(&KbBase[(size_t)r * D_ + g8], &SM[ci * 8]);
        gload16(&KaBase[(size_t)r * LY_ + g8], &SM[8192 + ci * 8]);
    }

    v8bf qf[4];
    {
        const ushort_t* q0 = QTg + (size_t)xg * U_ + h * D_;
        #pragma unroll
        for (int kt = 0; kt < 4; ++kt) qf[kt] = *(const v8bf*)&q0[(kt * 2 + hi) * 8];
    }

    v16f acc0, acc1;
    #pragma unroll
    for (int i = 0; i < 16; ++i) { acc0[i] = 0.f; acc1[i] = 0.f; }

    __syncthreads();

    #pragma unroll 2
    for (int tt = 0; tt < 16; ++tt) {
        ushort_t* KBc = SM + (tt & 1) * 4096;
        ushort_t* KAc = SM + 8192 + (tt & 1) * 4096;

        if (tt < 15) {
            ushort_t* KBn = SM + ((tt + 1) & 1) * 4096;
            ushort_t* KAn = SM + 8192 + ((tt + 1) & 1) * 4096;
            const int yn = tt * 64 + 64;
            #pragma unroll
            for (int e = 0; e < 2; ++e) {
                int ci = e * 256 + tid;
                int r = ci >> 3, c = ci & 7;
                int g8 = (c ^ (r & 7)) << 3;
                gload16(&KbBase[(size_t)(yn + r) * D_ + g8], &KBn[ci * 8]);
                gload16(&KaBase[(size_t)r * LY_ + yn + g8], &KAn[ci * 8]);
            }
        }
        v2u wb = *(const v2u*)&mbits[(size_t)xg * 32 + tt * 2];

        v8bf fr0[2], fr1[2];
        {
            v16f s;
            #pragma unroll
            for (int i = 0; i < 16; ++i) s[i] = 0.f;
            #pragma unroll
            for (int kt = 0; kt < 4; ++kt) {
                int ch = kt * 2 + hi;
                v8bf a = *(v8bf*)&KBc[lo * 64 + ((ch ^ (lo & 7)) << 3)];
                s = __builtin_amdgcn_mfma_f32_32x32x16_bf16(a, qf[kt], s, 0, 0, 0);
            }
            conv_sblock(s, wb[0] >> (hi * 8), fr0);
        }
        {
            v16f s;
            #pragma unroll
            for (int i = 0; i < 16; ++i) s[i] = 0.f;
            #pragma unroll
            for (int kt = 0; kt < 4; ++kt) {
                int ch = kt * 2 + hi;
                v8bf a = *(v8bf*)&KBc[(32 + lo) * 64 + ((ch ^ ((32 + lo) & 7)) << 3)];
                s = __builtin_amdgcn_mfma_f32_32x32x16_bf16(a, qf[kt], s, 0, 0, 0);
            }
            conv_sblock(s, wb[1] >> (hi * 8), fr1);
        }

        #pragma unroll
        for (int kt = 0; kt < 4; ++kt) {
            int ch = kt * 2 + hi;
            v8bf frk = (kt < 2) ? fr0[kt] : fr1[kt - 2];
            v8bf a0 = *(v8bf*)&KAc[lo * 64 + ((ch ^ (lo & 7)) << 3)];
            v8bf a1 = *(v8bf*)&KAc[(32 + lo) * 64 + ((ch ^ ((32 + lo) & 7)) << 3)];
            acc0 = __builtin_amdgcn_mfma_f32_32x32x16_bf16(a0, frk, acc0, 0, 0, 0);
            acc1 = __builtin_amdgcn_mfma_f32_32x32x16_bf16(a1, frk, acc1, 0, 0, 0);
        }
        __syncthreads();
    }

    {
        ushort_t* Et = SM;
        const int xl = xq + lo;
        float invn = 0.0625f / nel[xg];
        const ushort_t* qg = QTg + (size_t)xg * U_ + h * D_ + 4 * hi;
        #pragma unroll
        for (int half = 0; half < 2; ++half) {
            const v16f& c = half ? acc1 : acc0;
            #pragma unroll
            for (int q = 0; q < 4; ++q) {
                int d0 = half * 32 + q * 8 + 4 * hi;
                ushort_t q4[4];
                *(uint2*)q4 = *(const uint2*)&qg[half * 32 + q * 8];
                ushort_t e4[4];
                e4[0] = bf16u(0.5f * bfu2f(q4[0]) + c[q * 4 + 0] * invn);
                e4[1] = bf16u(0.5f * bfu2f(q4[1]) + c[q * 4 + 1] * invn);
                e4[2] = bf16u(0.5f * bfu2f(q4[2]) + c[q * 4 + 2] * invn);
                e4[3] = bf16u(0.5f * bfu2f(q4[3]) + c[q * 4 + 3] * invn);
                int base = xl * 64 + ((((d0 >> 3) ^ (xl & 7)) << 3) | (4 * hi));
                *(uint2*)&Et[base] = *(uint2*)e4;
            }
        }
    }
    __syncthreads();
    #pragma unroll
    for (int e = 0; e < 4; ++e) {
        int idx = e * 256 + tid;
        int row = idx >> 3, cc = idx & 7;
        uint4 v = *(const uint4*)&SM[row * 64 + ((cc ^ (row & 7)) << 3)];
        *(uint4*)&ETg[((size_t)(bx + row)) * U_ + h * D_ + cc * 8] = v;
    }
}

// ---------------------------------------------------------------------------
extern "C" void kernel_launch(void* const* d_in, const int* in_sizes, int n_in,
                              void* d_out, int out_size, void* d_ws, size_t ws_size,
                              hipStream_t stream) {
    const float* x    = (const float*)d_in[0];
    const float* y    = (const float*)d_in[1];
    const void*  mask = d_in[2];
    const float* wq   = (const float*)d_in[3];
    const float* wk   = (const float*)d_in[4];
    const float* wo   = (const float*)d_in[5];

    // ws layout (bytes):
    //   [0,        16777216)  xT bf16   -> later ET bf16
    //   [16777216, 33554432)  yT bf16
    //   [33554432, 50331648)  Ka bf16
    //   [50331648, 50855936)  wq bf16
    //   [50855936, 51380224)  wk bf16
    //   [51380224, 51904512)  wo bf16
    //   [51904512, 54001664)  maskBits u32
    //   [54001664, 54067200)  nel f32
    // d_out (33.5 MB fp32) moonlights as: QT bf16 [0,16MB) | Kb bf16 [16MB,32MB)
    char* wsb = (char*)d_ws;
    ushort_t* xT    = (ushort_t*)(wsb);
    ushort_t* yT    = (ushort_t*)(wsb + 16777216);
    ushort_t* Ka    = (ushort_t*)(wsb + 33554432);
    ushort_t* wqb   = (ushort_t*)(wsb + 50331648);
    ushort_t* wkb   = (ushort_t*)(wsb + 50855936);
    ushort_t* wob   = (ushort_t*)(wsb + 51380224);
    uint_t*   mbits = (uint_t*)(wsb + 51904512);
    float*    nel   = (float*)(wsb + 54001664);
    ushort_t* ET    = xT;                 // alias: xT dead after Q-GEMM
    ushort_t* QT    = (ushort_t*)d_out;                         // [0, 16MB)
    ushort_t* Kb    = (ushort_t*)d_out + (size_t)B_ * LX_ * U_; // [16MB, 32MB)

    castT_kernel<<<4096, 256, 0, stream>>>(x, y, xT, yT);
    nelw_kernel<<<4864, 256, 0, stream>>>(mask, wq, wk, wo, wqb, wkb, wob, nel, mbits);
    gemm_qk<<<1024, 256, 0, stream>>>(xT, wqb, wkb, yT, QT, Ka, Kb);
    attn_mfma<<<1024, 256, 0, stream>>>(QT, Ka, Kb, mbits, nel, ET);
    // out[b][u][x] fp32 = wo (M=512) x ET[b] (N=1024)
    gemm_mfma<1><<<dim3(8, 4, B_), 256, 0, stream>>>(
        wob, 0, ET, (size_t)LX_ * U_, d_out, (size_t)U_ * LX_, LX_);
}